// Round 4
// baseline (44.028 us; speedup 1.0000x reference)
//
#include <hip/hip_runtime.h>
#include <hip/hip_bf16.h>

// Problem constants (from reference): B=16, N2=1024, N3=2048, D=128
#define NB   16
#define N2   1024
#define N3   2048
#define DD   128
#define OROWS (N3 + 1)   // 2049
#define OCOLS (N2 + 1)   // 1025

typedef __attribute__((ext_vector_type(8))) __bf16 bf16x8;
typedef __attribute__((ext_vector_type(4))) float  f32x4;

// Pack two f32 into one u32 of 2x bf16 (RNE). a -> low half, b -> high half.
static __device__ __forceinline__ unsigned pack_bf16x2(float a, float b) {
    unsigned ua = __float_as_uint(a);
    ua = (ua + 0x7FFF + ((ua >> 16) & 1)) >> 16;
    unsigned ub = __float_as_uint(b);
    ub = (ub + 0x7FFF + ((ub >> 16) & 1)) & 0xFFFF0000u;
    return ua | ub;
}

// Fully fused: normalize(d3) x normalize(d2)^T -> padded sim, one kernel.
// One block = one 128(M) x 1024(N) output slab. Grid = 256 = 1 block/CU.
// A tile: reg-staged from f32, normalized, cvt to bf16, ds_written swizzled
// (st-16x32: byte ^= (row&7)<<4), then hoisted to registers once.
// B panel: 16 chunks of 64 rows, double-buffered; per iter: issue f32 loads
// for chunk nj+1 FIRST (latency hides under this iter), compute chunk nj,
// store 128x64 f32 outputs (never waited in-loop), then norm+cvt+ds_write
// chunk nj+1. One raw s_barrier per iter; all waits are compiler-counted
// (reg-staging keeps output stores outstanding across barriers).
__global__ __launch_bounds__(512, 1)
void fused_kernel(const float* __restrict__ d2,   // [NB*N2, 128] f32
                  const float* __restrict__ d3,   // [NB*N3, 128] f32
                  float* __restrict__ out) {
    __shared__ __align__(16) char smem[65536]; // A:[0,32K) B0:[32K,48K) B1:[48K,64K)

    // Bijective XCD swizzle: 256 blocks = 8 XCDs x 32; each XCD owns 2 whole
    // batches -> B f32 panels (1 MB) L2-resident per XCD.
    const int hw  = blockIdx.x;
    const int blk = (hw & 7) * 32 + (hw >> 3);
    const int b   = blk >> 4;           // batch
    const int ti  = blk & 15;           // M tile (128 rows of N3=2048)

    const int t = threadIdx.x;

    const float* gA = d3 + ((size_t)(b * N3 + ti * 128)) * DD;
    const float* gB = d2 + ((size_t)b * N2) * DD;

    // ---- Prologue: stage A (f32 -> norm -> bf16 -> swizzled LDS) ----
    const int arow  = t >> 2;           // 0..127
    const int apart = t & 3;            // 128-B f32 part (32 f32)
    float4 av[8];
    #pragma unroll
    for (int i = 0; i < 8; ++i)
        av[i] = *reinterpret_cast<const float4*>(gA + (size_t)arow * DD + apart * 32 + i * 4);

    // B chunk 0 loads issued alongside (independent).
    const int brow  = t >> 3;           // 0..63
    const int bpart = t & 7;            // 64-B f32 part (16 f32)
    float4 bv[4];
    #pragma unroll
    for (int i = 0; i < 4; ++i)
        bv[i] = *reinterpret_cast<const float4*>(gB + (size_t)brow * DD + bpart * 16 + i * 4);

    {   // A norms: reduce over 4 lanes (t&3)
        float ss = 0.f;
        #pragma unroll
        for (int i = 0; i < 8; ++i)
            ss += av[i].x * av[i].x + av[i].y * av[i].y + av[i].z * av[i].z + av[i].w * av[i].w;
        ss += __shfl_xor(ss, 1);
        ss += __shfl_xor(ss, 2);
        const float s = rsqrtf(ss);
        const int aswz = (arow & 7) << 4;
        #pragma unroll
        for (int j = 0; j < 4; ++j) {   // uint4 j covers f32 elems [8j, 8j+8)
            uint4 w;
            w.x = pack_bf16x2(av[2*j].x * s,   av[2*j].y * s);
            w.y = pack_bf16x2(av[2*j].z * s,   av[2*j].w * s);
            w.z = pack_bf16x2(av[2*j+1].x * s, av[2*j+1].y * s);
            w.w = pack_bf16x2(av[2*j+1].z * s, av[2*j+1].w * s);
            int colb = apart * 64 + j * 16;
            *reinterpret_cast<uint4*>(smem + arow * 256 + (colb ^ aswz)) = w;
        }
    }
    {   // B chunk 0 norms: reduce over 8 lanes (t&7)
        float ss = 0.f;
        #pragma unroll
        for (int i = 0; i < 4; ++i)
            ss += bv[i].x * bv[i].x + bv[i].y * bv[i].y + bv[i].z * bv[i].z + bv[i].w * bv[i].w;
        ss += __shfl_xor(ss, 1);
        ss += __shfl_xor(ss, 2);
        ss += __shfl_xor(ss, 4);
        const float s = rsqrtf(ss);
        const int bswz = (brow & 7) << 4;
        #pragma unroll
        for (int j = 0; j < 2; ++j) {
            uint4 w;
            w.x = pack_bf16x2(bv[2*j].x * s,   bv[2*j].y * s);
            w.y = pack_bf16x2(bv[2*j].z * s,   bv[2*j].w * s);
            w.z = pack_bf16x2(bv[2*j+1].x * s, bv[2*j+1].y * s);
            w.w = pack_bf16x2(bv[2*j+1].z * s, bv[2*j+1].w * s);
            int colb = bpart * 32 + j * 16;
            *reinterpret_cast<uint4*>(smem + 32768 + brow * 256 + (colb ^ bswz)) = w;
        }
    }
    asm volatile("s_waitcnt lgkmcnt(0)" ::: "memory");
    __builtin_amdgcn_s_barrier();
    __builtin_amdgcn_sched_barrier(0);

    // ---- Hoist A fragments to registers (A LDS is read-only afterwards) ----
    const int wid = t >> 6;             // 8 waves
    const int l   = t & 63;
    const int wm  = (wid >> 2) * 64;    // 0 / 64  : wave's M offset
    const int wn  = (wid & 3) * 16;     // 0..48   : wave's N offset in 64-col chunk
    const int lr  = l & 15;
    const int kq  = l >> 4;
    const int sw  = (lr & 7) << 4;

    bf16x8 af[4][4];   // [ks][mi]
    #pragma unroll
    for (int ks = 0; ks < 4; ++ks) {
        const int kb = ks * 64 + kq * 16;
        #pragma unroll
        for (int mi = 0; mi < 4; ++mi) {
            int r = wm + mi * 16 + lr;
            af[ks][mi] = *reinterpret_cast<const bf16x8*>(smem + r * 256 + (kb ^ sw));
        }
    }

    float* obase = out + (size_t)b * OROWS * OCOLS + (size_t)(ti * 128) * OCOLS;

    // ---- Main loop over 16 B chunks ----
    for (int nj = 0; nj < 16; ++nj) {
        // 1. Issue f32 loads for chunk nj+1 (latency hidden under this iter).
        if (nj < 15) {
            const float* gc = gB + (size_t)(nj + 1) * 64 * DD;
            #pragma unroll
            for (int i = 0; i < 4; ++i)
                bv[i] = *reinterpret_cast<const float4*>(gc + (size_t)brow * DD + bpart * 16 + i * 4);
        }

        // 2. Compute 128x64 chunk nj from buf(nj&1).
        const char* bbuf = smem + 32768 + (nj & 1) * 16384;
        f32x4 acc[4] = {};
        #pragma unroll
        for (int ks = 0; ks < 4; ++ks) {
            const int kb = ks * 64 + kq * 16;
            bf16x8 bfr = *reinterpret_cast<const bf16x8*>(bbuf + (wn + lr) * 256 + (kb ^ sw));
            #pragma unroll
            for (int mi = 0; mi < 4; ++mi)
                acc[mi] = __builtin_amdgcn_mfma_f32_16x16x32_bf16(
                    af[ks][mi], bfr, acc[mi], 0, 0, 0);
        }

        // 3. Stores (C/D layout: col=lane&15, row=(lane>>4)*4+reg). Never
        //    waited in-loop; they drain at HBM pace while we keep going.
        #pragma unroll
        for (int mi = 0; mi < 4; ++mi) {
            #pragma unroll
            for (int i = 0; i < 4; ++i) {
                int r = wm + mi * 16 + kq * 4 + i;
                int c = nj * 64 + wn + lr;
                obase[(size_t)r * OCOLS + c] = acc[mi][i];
            }
        }

        // 4. Normalize + cvt + ds_write chunk nj+1 into buf((nj+1)&1).
        //    (Compiler waits vmcnt counted so the 16 stores stay in flight.)
        if (nj < 15) {
            float ss = 0.f;
            #pragma unroll
            for (int i = 0; i < 4; ++i)
                ss += bv[i].x * bv[i].x + bv[i].y * bv[i].y + bv[i].z * bv[i].z + bv[i].w * bv[i].w;
            ss += __shfl_xor(ss, 1);
            ss += __shfl_xor(ss, 2);
            ss += __shfl_xor(ss, 4);
            const float s = rsqrtf(ss);
            const int bswz = (brow & 7) << 4;
            char* nb = smem + 32768 + ((nj + 1) & 1) * 16384;
            #pragma unroll
            for (int j = 0; j < 2; ++j) {
                uint4 w;
                w.x = pack_bf16x2(bv[2*j].x * s,   bv[2*j].y * s);
                w.y = pack_bf16x2(bv[2*j].z * s,   bv[2*j].w * s);
                w.z = pack_bf16x2(bv[2*j+1].x * s, bv[2*j+1].y * s);
                w.w = pack_bf16x2(bv[2*j+1].z * s, bv[2*j+1].w * s);
                int colb = bpart * 32 + j * 16;
                *reinterpret_cast<uint4*>(nb + brow * 256 + (colb ^ bswz)) = w;
            }
            asm volatile("s_waitcnt lgkmcnt(0)" ::: "memory");
        }
        asm volatile("" ::: "memory");
        __builtin_amdgcn_s_barrier();
        __builtin_amdgcn_sched_barrier(0);
    }

    // ---- Dustbin: col 1024 for this slab's rows; row 2048 once per batch ----
    if (t < 128)
        obase[(size_t)t * OCOLS + N2] = 0.0f;
    if (ti == 15) {
        float* last = out + (size_t)b * OROWS * OCOLS + (size_t)N3 * OCOLS;
        for (int c = t; c < OCOLS; c += 512) last[c] = 0.0f;
    }
}

extern "C" void kernel_launch(void* const* d_in, const int* in_sizes, int n_in,
                              void* d_out, int out_size, void* d_ws, size_t ws_size,
                              hipStream_t stream) {
    (void)in_sizes; (void)n_in; (void)out_size; (void)d_ws; (void)ws_size;
    const float* desc2d = (const float*)d_in[0];
    const float* desc3d = (const float*)d_in[2];
    float* out = (float*)d_out;

    fused_kernel<<<NB * (N3 / 128), 512, 0, stream>>>(desc2d, desc3d, out);
}